// Round 5
// baseline (625.178 us; speedup 1.0000x reference)
//
#include <hip/hip_runtime.h>
#include <cstdint>
#include <cstddef>

// Sizes (fixed): B=512, N=200, F=32, E=H=128, L=2, 4H=512
#define LEAK 0.01f
#define L2E 1.4426950408889634f

typedef _Float16 f16;
typedef __attribute__((ext_vector_type(4))) _Float16 f16x4;
typedef __attribute__((ext_vector_type(8))) _Float16 f16x8;
typedef __attribute__((ext_vector_type(4))) float f32x4;

static __device__ __forceinline__ f16x8 pack8s(float4 a, float4 b, float s) {
  f16x8 r;
  r[0] = (f16)(a.x * s); r[1] = (f16)(a.y * s); r[2] = (f16)(a.z * s); r[3] = (f16)(a.w * s);
  r[4] = (f16)(b.x * s); r[5] = (f16)(b.y * s); r[6] = (f16)(b.z * s); r[7] = (f16)(b.w * s);
  return r;
}
static __device__ __forceinline__ f16x8 pack8(float4 a, float4 b) {
  return pack8s(a, b, 1.0f);
}
#define MFMA16(a, b, c) __builtin_amdgcn_mfma_f32_16x16x32_f16((a), (b), (c), 0, 0, 0)

// Barrier that drains ONLY LDS ops (lgkmcnt), leaving global loads/stores
// (vmcnt) in flight across the barrier.
static __device__ __forceinline__ void barrier_lds() {
  asm volatile("s_waitcnt lgkmcnt(0)\n\ts_barrier" ::: "memory");
}

// gate scale: i,f,o preacts in log2 units; g in 2*log2 units
__constant__ float SCG[4] = {L2E, L2E, 2.0f * L2E, L2E};

// ---------------------------------------------------------------------------
// k_emb: e[t][b][j] = leaky_relu(x[b][t][:] . w_emb[j][:] + b_emb[j]), f16
// ---------------------------------------------------------------------------
__global__ __launch_bounds__(256) void k_emb(
    const float* __restrict__ x, const float* __restrict__ wemb,
    const float* __restrict__ bemb, f16* __restrict__ e) {
  const int t = blockIdx.x, tid = threadIdx.x;
  __shared__ __align__(16) float wl[128 * 32];
  __shared__ float bl[128];
  for (int idx = tid; idx < 1024; idx += 256)
    ((float4*)wl)[idx] = ((const float4*)wemb)[idx];
  if (tid < 128) bl[tid] = bemb[tid];

  float xa[32], xb[32];
  const float* xpa = x + ((size_t)tid * 200 + t) * 32;
  const float* xpb = x + ((size_t)(tid + 256) * 200 + t) * 32;
#pragma unroll
  for (int k4 = 0; k4 < 8; ++k4) {
    float4 va = *(const float4*)(xpa + k4 * 4);
    float4 vb = *(const float4*)(xpb + k4 * 4);
    xa[k4 * 4 + 0] = va.x; xa[k4 * 4 + 1] = va.y; xa[k4 * 4 + 2] = va.z; xa[k4 * 4 + 3] = va.w;
    xb[k4 * 4 + 0] = vb.x; xb[k4 * 4 + 1] = vb.y; xb[k4 * 4 + 2] = vb.z; xb[k4 * 4 + 3] = vb.w;
  }
  __syncthreads();

  f16* ea = e + ((size_t)t * 512 + tid) * 128;
  f16* eb = e + ((size_t)t * 512 + tid + 256) * 128;
  for (int j8 = 0; j8 < 16; ++j8) {
    f16x8 oa, ob;
#pragma unroll
    for (int jj = 0; jj < 8; ++jj) {
      int j = j8 * 8 + jj;
      float aa = bl[j], ab = bl[j];
#pragma unroll
      for (int k4 = 0; k4 < 8; ++k4) {
        float4 wv = *(const float4*)&wl[j * 32 + k4 * 4];
        aa += xa[k4 * 4 + 0] * wv.x + xa[k4 * 4 + 1] * wv.y +
              xa[k4 * 4 + 2] * wv.z + xa[k4 * 4 + 3] * wv.w;
        ab += xb[k4 * 4 + 0] * wv.x + xb[k4 * 4 + 1] * wv.y +
              xb[k4 * 4 + 2] * wv.z + xb[k4 * 4 + 3] * wv.w;
      }
      oa[jj] = (f16)(aa >= 0.f ? aa : LEAK * aa);
      ob[jj] = (f16)(ab >= 0.f ? ab : LEAK * ab);
    }
    *(f16x8*)(ea + j8 * 8) = oa;
    *(f16x8*)(eb + j8 * 8) = ob;
  }
}

// ---------------------------------------------------------------------------
// xp_waves: x-projection worker (device fn). Wave task `task` owns slice
// ct = task&7 (16 hidden cols x 4 gates, weights PRE-SCALED by SCG);
// persistent loop: task = wid, wid+stride, ... < ntasks (stride % 8 == 0
// keeps ct invariant). xp layout: [tl][16batch x 512gates] blocks of
// (bt,ct): lane (q,l16) stores 16 f16 = gates {i,f,g,o} x rows q*4..+3.
// ---------------------------------------------------------------------------
static __device__ __forceinline__ void xp_waves(
    const f16* __restrict__ e, const float* __restrict__ wih,
    const float* __restrict__ bih, const float* __restrict__ bhh,
    f16* __restrict__ xp, int t0, int wid, int ntasks, int stride, int lane) {
  const int q = lane >> 4, l16 = lane & 15;
  const int ct = wid & 7;

  f16x8 BW[4][4];
  float bias[4];
#pragma unroll
  for (int G = 0; G < 4; ++G) {
    int n = G * 128 + ct * 16 + l16;
    bias[G] = (bih[n] + bhh[n]) * SCG[G];
#pragma unroll
    for (int kc = 0; kc < 4; ++kc) {
      const float4* p = (const float4*)(wih + (size_t)n * 128 + kc * 32 + q * 8);
      BW[G][kc] = pack8s(p[0], p[1], SCG[G]);
    }
  }
  for (int task = wid; task < ntasks; task += stride) {
    int g2 = task >> 3;
    int tl = g2 >> 2, btg = g2 & 3;
#pragma unroll
    for (int p = 0; p < 8; ++p) {
      int bt = btg * 8 + p;
      const f16* A = e + ((size_t)(t0 + tl) * 512 + bt * 16 + l16) * 128 + q * 8;
      f16x8 af[4];
#pragma unroll
      for (int kc = 0; kc < 4; ++kc) af[kc] = *(const f16x8*)(A + kc * 32);
      f32x4 acc[4];
#pragma unroll
      for (int G = 0; G < 4; ++G)
        acc[G] = (f32x4){bias[G], bias[G], bias[G], bias[G]};
#pragma unroll
      for (int kc = 0; kc < 4; ++kc)
#pragma unroll
        for (int G = 0; G < 4; ++G)
          acc[G] = MFMA16(af[kc], BW[G][kc], acc[G]);
      f16x8 oA, oB;
#pragma unroll
      for (int r = 0; r < 4; ++r) {
        oA[r]     = (f16)acc[0][r];
        oA[4 + r] = (f16)acc[1][r];
        oB[r]     = (f16)acc[2][r];
        oB[4 + r] = (f16)acc[3][r];
      }
      f16* dst = xp + (size_t)tl * 262144 + bt * 8192 + ct * 1024 + lane * 16;
      *(f16x8*)dst = oA;
      *(f16x8*)(dst + 8) = oB;
    }
  }
}

__global__ __launch_bounds__(256, 2) void k_xp(
    const f16* __restrict__ e, const float* __restrict__ wih,
    const float* __restrict__ bih, const float* __restrict__ bhh,
    f16* __restrict__ xp, int t0) {
  const int nt = gridDim.x * 4;  // one task per wave
  xp_waves(e, wih, bih, bhh, xp, t0,
           blockIdx.x * 4 + (threadIdx.x >> 6), nt, nt, threadIdx.x & 63);
}

// ---------------------------------------------------------------------------
// rec_body: LSTM recurrence (h @ Whh^T + precomputed scaled xp chunk).
// 64 blocks x 8 batch rows, 512 thr. Wave w owns hidden cols w*16..+15 for
// all 4 gates. A-fragment: all lanes read row l16&7 (rows 8-15 of the MFMA
// output are dead -- duplicated A rows are harmless, no masking/zeroing).
// Cell math: lanes q<2 process their 4 acc rows directly (rows q*4+r,
// r=0..3) -- NO cross-lane shfl redistribute (keeps the LDS pipe and the
// step's latency chain free of ds_bpermute). Per-step barrier drains only
// lgkmcnt so the 2-step xp prefetch + hs store stay in flight.
// State hws/cws: f32x4 per (block, wave, lane<32).
// ---------------------------------------------------------------------------
static __device__ __forceinline__ void rec_body(
    const f16* __restrict__ xp, const float* __restrict__ whh,
    float* __restrict__ hws, float* __restrict__ cws,
    f16* __restrict__ hs, int layer, int t0, int CH, int bt) {
  const int tid = threadIdx.x;
  const int w = tid >> 6, lane = tid & 63, q = lane >> 4, l16 = lane & 15;
  __shared__ __align__(16) f16 hlds[2][8][136];  // double-buffered h (8 rows)

  f16x8 BH[4][4];  // Whh B-fragments, pre-scaled per gate
#pragma unroll
  for (int G = 0; G < 4; ++G) {
    int n = G * 128 + w * 16 + l16;
#pragma unroll
    for (int kc = 0; kc < 4; ++kc) {
      const float4* ph = (const float4*)(whh + (size_t)n * 128 + kc * 32 + q * 8);
      BH[G][kc] = pack8s(ph[0], ph[1], SCG[G]);
    }
  }

  f32x4 cst = (f32x4){0.f, 0.f, 0.f, 0.f};
  if (layer == 0 && t0 == 0) {
    for (int idx = tid; idx < 8 * 136; idx += 512)
      (&hlds[1][0][0])[idx] = (f16)0.f;
  } else if (q < 2) {
    cst = *(const f32x4*)(cws + ((size_t)(bt * 8 + w) * 32 + lane) * 4);
    f32x4 hv = *(const f32x4*)(hws + ((size_t)(bt * 8 + w) * 32 + lane) * 4);
#pragma unroll
    for (int r = 0; r < 4; ++r)
      hlds[1][q * 4 + r][w * 16 + l16] = (f16)hv[r];
  }
  barrier_lds();

  // xp read: block covers old 16-batch group g16=bt>>1, half=bt&1.
  // lane (q,l16) wants rows (bt&1)*8 + q*4+r (valid q<2) -> old lane
  // qo = (bt&1)*2 + (q&1) (q&1 keeps q>=2 lanes in bounds; data unused).
  const int qo = (bt & 1) * 2 + (q & 1);
  const f16* xpl = xp + (((size_t)(bt >> 1) * 8 + w) * 64 + qo * 16 + l16) * 16;
  f16x8 xa = *(const f16x8*)(xpl);
  f16x8 xb = *(const f16x8*)(xpl + 8);
  const int t1 = (CH > 1) ? 1 : 0;
  f16x8 n1a = *(const f16x8*)(xpl + (size_t)t1 * 262144);
  f16x8 n1b = *(const f16x8*)(xpl + (size_t)t1 * 262144 + 8);

  f32x4 hk = (f32x4){0.f, 0.f, 0.f, 0.f};
  for (int tl = 0; tl < CH; ++tl) {
    int tn2 = (tl + 2 < CH) ? tl + 2 : CH - 1;
    const f16* xpn = xpl + (size_t)tn2 * 262144;
    f16x8 n2a = *(const f16x8*)(xpn);
    f16x8 n2b = *(const f16x8*)(xpn + 8);

    const int rb = (tl + 1) & 1;
    f16x8 ah[4];
#pragma unroll
    for (int kc = 0; kc < 4; ++kc)
      ah[kc] = *(const f16x8*)&hlds[rb][l16 & 7][kc * 32 + q * 8];

    f32x4 acc[4];
#pragma unroll
    for (int r = 0; r < 4; ++r) {
      acc[0][r] = (float)xa[r];
      acc[1][r] = (float)xa[4 + r];
      acc[2][r] = (float)xb[r];
      acc[3][r] = (float)xb[4 + r];
    }
#pragma unroll
    for (int kc = 0; kc < 4; ++kc)
#pragma unroll
      for (int G = 0; G < 4; ++G)
        acc[G] = MFMA16(ah[kc], BH[G][kc], acc[G]);

    const int wb = tl & 1;
    if (q < 2) {
#pragma unroll
      for (int r = 0; r < 4; ++r) {
        // acc: [0]=i', [1]=f', [2]=g'(x2 scale), [3]=o'  (log2 units)
        float ui = __builtin_amdgcn_exp2f(-acc[0][r]);
        float uf = __builtin_amdgcn_exp2f(-acc[1][r]);
        float ug = __builtin_amdgcn_exp2f(-fmaxf(acc[2][r], -88.f));
        float uo = __builtin_amdgcn_exp2f(-acc[3][r]);
        float sf = __builtin_amdgcn_rcpf(1.0f + uf);
        float p1 = (1.0f - ug) * __builtin_amdgcn_rcpf((1.0f + ui) * (1.0f + ug));
        float cc = sf * cst[r] + p1;               // new cell state
        cst[r] = cc;
        float ccl = fminf(fmaxf(cc, -30.f), 30.f) * (-2.0f * L2E);
        float ucc = __builtin_amdgcn_exp2f(ccl);
        float hv = (1.0f - ucc) * __builtin_amdgcn_rcpf((1.0f + uo) * (1.0f + ucc));
        hk[r] = hv;
        hlds[wb][q * 4 + r][w * 16 + l16] = (f16)hv;
      }
    }
    barrier_lds();
    if (layer != 0 && tid < 256) {
      const int srow = tid >> 5, scol = (tid & 31) * 4;  // 8 rows x 128 cols
      f16x4 hv4 = *(const f16x4*)&hlds[wb][srow][scol];
      *(f16x4*)(hs + ((size_t)(bt * 8 + srow) * 200 + (t0 + tl)) * 128 + scol) = hv4;
    }
    xa = n1a; xb = n1b; n1a = n2a; n1b = n2b;
  }

  if (q < 2) {
    *(f32x4*)(hws + ((size_t)(bt * 8 + w) * 32 + lane) * 4) = hk;
    *(f32x4*)(cws + ((size_t)(bt * 8 + w) * 32 + lane) * 4) = cst;
  }
}

__global__ __launch_bounds__(512, 2) void k_rec(
    const f16* __restrict__ xp, const float* __restrict__ whh,
    float* __restrict__ hws, float* __restrict__ cws,
    f16* __restrict__ hs, int layer, int t0, int CH) {
  rec_body(xp, whh, hws, cws, hs, layer, t0, CH, blockIdx.x);
}

// Merged, grid = 256 (1 block/CU): blocks 0..63 = recurrence chunk
// (layer, t0_r, CH=100, xp_r); blocks 64..255 = persistent x-projection
// (3200 tasks over 1536 waves) into DISJOINT xp_w (A/B ping-pong).
__global__ __launch_bounds__(512, 2) void k_recxp(
    const f16* __restrict__ xp_r, const float* __restrict__ whh,
    float* __restrict__ hws, float* __restrict__ cws,
    f16* __restrict__ hs, int layer, int t0_r,
    const f16* __restrict__ e, const float* __restrict__ wih_n,
    const float* __restrict__ bih_n, const float* __restrict__ bhh_n,
    f16* __restrict__ xp_w, int t0_x) {
  if (blockIdx.x < 64) {
    rec_body(xp_r, whh, hws, cws, hs, layer, t0_r, 100, blockIdx.x);
  } else {
    // 3200 wave-tasks (100 steps), 1536 waves, stride 1536 (mult of 8)
    xp_waves(e, wih_n, bih_n, bhh_n, xp_w, t0_x,
             (blockIdx.x - 64) * 8 + (threadIdx.x >> 6), 3200, 1536,
             threadIdx.x & 63);
  }
}

// ---------------------------------------------------------------------------
// k_head: per-batch fused fc1 -> leaky -> fc2 -> exp -> Sinkhorn -> psi.
// grid=512, block=512 (8 waves), dynamic LDS = 81600 B (2 WG/CU, 16 waves/CU).
// ---------------------------------------------------------------------------
__global__ __launch_bounds__(512, 4) void k_head(
    const f16* __restrict__ hs, const float* __restrict__ wfc1,
    const float* __restrict__ bfc1, const float* __restrict__ wfc2,
    const float* __restrict__ bfc2, float* __restrict__ psi) {
  extern __shared__ char smem[];
  f16* E = (f16*)smem;                      // [200][200]
  f16* o1 = (f16*)(smem + 27200);           // [200][136]
  float* uu = (float*)(smem + 80000);
  float* vv = (float*)(smem + 80800);
  const int b = blockIdx.x, tid = threadIdx.x;
  const int w = tid >> 6, lane = tid & 63, q = lane >> 4, l16 = lane & 15;
  const f16* A = hs + (size_t)b * 200 * 128;

  // fc1 weights: wave w -> cols w*16..+15
  f16x8 BF1[4];
  float bias1;
  {
    int n = w * 16 + l16;
    bias1 = bfc1[n];
#pragma unroll
    for (int kc = 0; kc < 4; ++kc) {
      const float4* p = (const float4*)(wfc1 + (size_t)n * 128 + kc * 32 + q * 8);
      BF1[kc] = pack8(p[0], p[1]);
    }
  }
  // fc2 weights: wave w -> ct = w, w+8
  f16x8 BF2[2][4];
  float bias2[2] = {0.f, 0.f};
#pragma unroll
  for (int ci = 0; ci < 2; ++ci) {
    int ct = w + ci * 8;
    if (ct < 13) {
      int n = ct * 16 + l16; if (n > 199) n = 199;
      bias2[ci] = bfc2[n];
#pragma unroll
      for (int kc = 0; kc < 4; ++kc) {
        const float4* p = (const float4*)(wfc2 + (size_t)n * 128 + kc * 32 + q * 8);
        BF2[ci][kc] = pack8(p[0], p[1]);
      }
    }
  }

  // fc1 -> leaky -> o1
  for (int rt = 0; rt < 13; ++rt) {
    int m = rt * 16 + l16; if (m > 199) m = 199;
    f16x8 af[4];
#pragma unroll
    for (int kc = 0; kc < 4; ++kc)
      af[kc] = *(const f16x8*)(A + (size_t)m * 128 + kc * 32 + q * 8);
    f32x4 acc = (f32x4){bias1, bias1, bias1, bias1};
#pragma unroll
    for (int kc = 0; kc < 4; ++kc) acc = MFMA16(af[kc], BF1[kc], acc);
    int col = w * 16 + l16;
#pragma unroll
    for (int r = 0; r < 4; ++r) {
      int row = rt * 16 + q * 4 + r;
      float vvv = acc[r]; vvv = vvv >= 0.f ? vvv : LEAK * vvv;
      if (row < 200) o1[row * 136 + col] = (f16)vvv;
    }
  }
  __syncthreads();

  // fc2 -> exp -> E
  for (int rt = 0; rt < 13; ++rt) {
    int m = rt * 16 + l16; if (m > 199) m = 199;
    f16x8 af[4];
#pragma unroll
    for (int kc = 0; kc < 4; ++kc)
      af[kc] = *(const f16x8*)&o1[m * 136 + kc * 32 + q * 8];
    __syncthreads();
#pragma unroll
    for (int ci = 0; ci < 2; ++ci) {
      int ct = w + ci * 8;
      if (ct < 13) {
        f32x4 acc = (f32x4){bias2[ci], bias2[ci], bias2[ci], bias2[ci]};
#pragma unroll
        for (int kc = 0; kc < 4; ++kc) acc = MFMA16(af[kc], BF2[ci][kc], acc);
        int col = ct * 16 + l16;
#pragma unroll
        for (int r = 0; r < 4; ++r) {
          int row = rt * 16 + q * 4 + r;
          if (row < 200 && col < 200) E[row * 200 + col] = (f16)__expf(acc[r]);
        }
      }
    }
  }
  __syncthreads();
  if (tid < 200) vv[tid] = 1.0f;
  __syncthreads();

  for (int it = 0; it < 5; ++it) {
    // row phase: r = tid>>1 (0..199), h = tid&1 sums 100 elements
    if (tid < 400) {
      int r = tid >> 1, h = tid & 1;
      const f16* Er = E + r * 200 + h * 100;
      const float* vp = vv + h * 100;
      float s0 = 0.f, s1 = 0.f;
      for (int j = 0; j < 100; j += 4) {
        f16x4 e4 = *(const f16x4*)(Er + j);
        float4 v4 = *(const float4*)(vp + j);
        s0 += (float)e4[0] * v4.x + (float)e4[1] * v4.y;
        s1 += (float)e4[2] * v4.z + (float)e4[3] * v4.w;
      }
      float s = s0 + s1;
      s += __shfl_xor(s, 1);
      if (h == 0) uu[r] = __builtin_amdgcn_rcpf(s);
    }
    __syncthreads();
    // col phase: c4 = tid>>3 (0..49) owns cols c4*4..+3; g = tid&7 owns rows g*25..+24
    if (tid < 400) {
      int c4 = tid >> 3, g = tid & 7;
      const f16* Ec = E + (size_t)(g * 25) * 200 + c4 * 4;
      float a0 = 0.f, a1 = 0.f, a2 = 0.f, a3 = 0.f;
      for (int i = 0; i < 25; ++i) {
        f16x4 e4 = *(const f16x4*)(Ec + i * 200);
        float ui = uu[g * 25 + i];
        a0 += (float)e4[0] * ui;
        a1 += (float)e4[1] * ui;
        a2 += (float)e4[2] * ui;
        a3 += (float)e4[3] * ui;
      }
#pragma unroll
      for (int mk = 1; mk <= 4; mk <<= 1) {
        a0 += __shfl_xor(a0, mk);
        a1 += __shfl_xor(a1, mk);
        a2 += __shfl_xor(a2, mk);
        a3 += __shfl_xor(a3, mk);
      }
      if (g == 0) {
        float4 o;
        o.x = __builtin_amdgcn_rcpf(a0);
        o.y = __builtin_amdgcn_rcpf(a1);
        o.z = __builtin_amdgcn_rcpf(a2);
        o.w = __builtin_amdgcn_rcpf(a3);
        *(float4*)(vv + c4 * 4) = o;
      }
    }
    __syncthreads();
  }

  float* P = psi + (size_t)b * 40000;
  for (int idx4 = tid; idx4 < 10000; idx4 += 512) {
    unsigned i = ((unsigned)idx4 * 5243u) >> 18;
    unsigned jq = (unsigned)idx4 - i * 50u;
    f16x4 e4 = *(const f16x4*)(E + i * 200 + jq * 4);
    float4 v4 = *(const float4*)(vv + jq * 4);
    float ui = uu[i];
    float4 o;
    o.x = ui * (float)e4[0] * v4.x;
    o.y = ui * (float)e4[1] * v4.y;
    o.z = ui * (float)e4[2] * v4.z;
    o.w = ui * (float)e4[3] * v4.w;
    *(float4*)(P + i * 200 + jq * 4) = o;
  }
}

// ---------------------------------------------------------------------------
extern "C" void kernel_launch(void* const* d_in, const int* in_sizes, int n_in,
                              void* d_out, int out_size, void* d_ws, size_t ws_size,
                              hipStream_t stream) {
  const float* x    = (const float*)d_in[0];
  const float* wemb = (const float*)d_in[1];
  const float* bemb = (const float*)d_in[2];
  const float* wih  = (const float*)d_in[3];
  const float* whh  = (const float*)d_in[4];
  const float* bih  = (const float*)d_in[5];
  const float* bhh  = (const float*)d_in[6];
  const float* wfc1 = (const float*)d_in[7];
  const float* bfc1 = (const float*)d_in[8];
  const float* wfc2 = (const float*)d_in[9];
  const float* bfc2 = (const float*)d_in[10];
  float* psi = (float*)d_out;

  char* ws = (char*)d_ws;
  f16*   e   = (f16*)(ws);                  // [200][512][128] f16 = 26,214,400 B
  float* hws = (float*)(ws + 26214400);     // 64x8x32x4 f32       =    262,144 B
  float* cws = (float*)(ws + 26476544);     //                     =    262,144 B
  f16*   hs  = (f16*)(ws + 26738688);       // [512][200][128] f16 = 26,214,400 B
  f16*   xpA = (f16*)(ws + 52953088);       // 100 steps x 512 x 512 f16 = 52,428,800 B
  f16*   xpB = (f16*)(ws + 105381888);      // 100 steps             = 52,428,800 B
  // pipelined total: 157,810,688 B

  const size_t fixed = 52953088;
  const bool pipelined = (ws_size >= 157810688ull);

  (void)hipFuncSetAttribute((const void*)k_head,
                            hipFuncAttributeMaxDynamicSharedMemorySize, 81600);

  k_emb<<<200, 256, 0, stream>>>(x, wemb, bemb, e);

  const float* wih1 = wih + 65536;  const float* whh1 = whh + 65536;
  const float* bih1 = bih + 512;    const float* bhh1 = bhh + 512;

  if (pipelined) {
    // A/B ping-pong, 100-step chunks; rec reads one buffer while the other
    // is being filled for the next chunk (disjoint within every launch).
    k_xp<<<800, 256, 0, stream>>>(e, wih, bih, bhh, xpA, 0);
    k_recxp<<<256, 512, 0, stream>>>(xpA, whh, hws, cws, hs, 0, 0,
                                     e, wih, bih, bhh, xpB, 100);
    k_recxp<<<256, 512, 0, stream>>>(xpB, whh, hws, cws, hs, 0, 100,
                                     e, wih1, bih1, bhh1, xpA, 0);
    k_recxp<<<256, 512, 0, stream>>>(xpA, whh1, hws, cws, hs, 1, 0,
                                     e, wih1, bih1, bhh1, xpB, 100);
    k_rec<<<64, 512, 0, stream>>>(xpB, whh1, hws, cws, hs, 1, 100, 100);
  } else {
    const int cands[] = {100, 50, 40, 25, 20, 10, 8, 5, 4, 2, 1};
    int CH = 1;
    for (int ci = 0; ci < 11; ++ci) {
      if (fixed + (size_t)cands[ci] * 524288 <= ws_size) { CH = cands[ci]; break; }
    }
    for (int l = 0; l < 2; ++l) {
      const float* wih_l = wih + (size_t)l * 65536;
      const float* whh_l = whh + (size_t)l * 65536;
      const float* bih_l = bih + (size_t)l * 512;
      const float* bhh_l = bhh + (size_t)l * 512;
      for (int t0 = 0; t0 < 200; t0 += CH) {
        k_xp<<<CH * 8, 256, 0, stream>>>(e, wih_l, bih_l, bhh_l, xpA, t0);
        k_rec<<<64, 512, 0, stream>>>(xpA, whh_l, hws, cws, hs, l, t0, CH);
      }
    }
  }
  k_head<<<512, 512, 81600, stream>>>(hs, wfc1, bfc1, wfc2, bfc2, psi);
}

// Round 6
// 547.581 us; speedup vs baseline: 1.1417x; 1.1417x over previous
//
#include <hip/hip_runtime.h>
#include <cstdint>
#include <cstddef>

// Sizes (fixed): B=512, N=200, F=32, E=H=128, L=2, 4H=512
#define LEAK 0.01f
#define L2E 1.4426950408889634f

typedef _Float16 f16;
typedef __attribute__((ext_vector_type(4))) _Float16 f16x4;
typedef __attribute__((ext_vector_type(8))) _Float16 f16x8;
typedef __attribute__((ext_vector_type(4))) float f32x4;
typedef __attribute__((ext_vector_type(2))) unsigned u32x2;

static __device__ __forceinline__ f16x8 pack8s(float4 a, float4 b, float s) {
  f16x8 r;
  r[0] = (f16)(a.x * s); r[1] = (f16)(a.y * s); r[2] = (f16)(a.z * s); r[3] = (f16)(a.w * s);
  r[4] = (f16)(b.x * s); r[5] = (f16)(b.y * s); r[6] = (f16)(b.z * s); r[7] = (f16)(b.w * s);
  return r;
}
static __device__ __forceinline__ f16x8 pack8(float4 a, float4 b) {
  return pack8s(a, b, 1.0f);
}
#define MFMA16(a, b, c) __builtin_amdgcn_mfma_f32_16x16x32_f16((a), (b), (c), 0, 0, 0)

// Barrier that drains ONLY LDS ops (lgkmcnt), leaving global loads/stores
// (vmcnt) in flight across the barrier.
static __device__ __forceinline__ void barrier_lds() {
  asm volatile("s_waitcnt lgkmcnt(0)\n\ts_barrier" ::: "memory");
}

// VALU-pipe lane swap: returns {lanes 0-31: a, lanes 32-63: b from lanes 0-31}
// == (q<2 ? a : __shfl_xor(b,32)) -- replaces ds_bpermute on the LDS pipe.
static __device__ __forceinline__ float permswap_lo(float a, float b) {
  u32x2 r = __builtin_amdgcn_permlane32_swap(__float_as_uint(a),
                                             __float_as_uint(b), false, false);
  return __uint_as_float(r[0]);
}

// gate scale: i,f,o preacts in log2 units; g in 2*log2 units
__constant__ float SCG[4] = {L2E, L2E, 2.0f * L2E, L2E};

// ---------------------------------------------------------------------------
// k_emb: e[t][b][j] = leaky_relu(x[b][t][:] . w_emb[j][:] + b_emb[j]), f16
// ---------------------------------------------------------------------------
__global__ __launch_bounds__(256) void k_emb(
    const float* __restrict__ x, const float* __restrict__ wemb,
    const float* __restrict__ bemb, f16* __restrict__ e) {
  const int t = blockIdx.x, tid = threadIdx.x;
  __shared__ __align__(16) float wl[128 * 32];
  __shared__ float bl[128];
  for (int idx = tid; idx < 1024; idx += 256)
    ((float4*)wl)[idx] = ((const float4*)wemb)[idx];
  if (tid < 128) bl[tid] = bemb[tid];

  float xa[32], xb[32];
  const float* xpa = x + ((size_t)tid * 200 + t) * 32;
  const float* xpb = x + ((size_t)(tid + 256) * 200 + t) * 32;
#pragma unroll
  for (int k4 = 0; k4 < 8; ++k4) {
    float4 va = *(const float4*)(xpa + k4 * 4);
    float4 vb = *(const float4*)(xpb + k4 * 4);
    xa[k4 * 4 + 0] = va.x; xa[k4 * 4 + 1] = va.y; xa[k4 * 4 + 2] = va.z; xa[k4 * 4 + 3] = va.w;
    xb[k4 * 4 + 0] = vb.x; xb[k4 * 4 + 1] = vb.y; xb[k4 * 4 + 2] = vb.z; xb[k4 * 4 + 3] = vb.w;
  }
  __syncthreads();

  f16* ea = e + ((size_t)t * 512 + tid) * 128;
  f16* eb = e + ((size_t)t * 512 + tid + 256) * 128;
  for (int j8 = 0; j8 < 16; ++j8) {
    f16x8 oa, ob;
#pragma unroll
    for (int jj = 0; jj < 8; ++jj) {
      int j = j8 * 8 + jj;
      float aa = bl[j], ab = bl[j];
#pragma unroll
      for (int k4 = 0; k4 < 8; ++k4) {
        float4 wv = *(const float4*)&wl[j * 32 + k4 * 4];
        aa += xa[k4 * 4 + 0] * wv.x + xa[k4 * 4 + 1] * wv.y +
              xa[k4 * 4 + 2] * wv.z + xa[k4 * 4 + 3] * wv.w;
        ab += xb[k4 * 4 + 0] * wv.x + xb[k4 * 4 + 1] * wv.y +
              xb[k4 * 4 + 2] * wv.z + xb[k4 * 4 + 3] * wv.w;
      }
      oa[jj] = (f16)(aa >= 0.f ? aa : LEAK * aa);
      ob[jj] = (f16)(ab >= 0.f ? ab : LEAK * ab);
    }
    *(f16x8*)(ea + j8 * 8) = oa;
    *(f16x8*)(eb + j8 * 8) = ob;
  }
}

// ---------------------------------------------------------------------------
// xp_waves: x-projection worker (device fn). Wave task `task` owns slice
// ct = task&7 (16 hidden cols x 4 gates, weights PRE-SCALED by SCG);
// persistent loop: task = wid, wid+stride, ... < ntasks (stride % 8 == 0
// keeps ct invariant). xp layout: [tl][16batch x 512gates] blocks of
// (bt,ct): lane (q,l16) stores 16 f16 = gates {i,f,g,o} x rows q*4..+3.
// ---------------------------------------------------------------------------
static __device__ __forceinline__ void xp_waves(
    const f16* __restrict__ e, const float* __restrict__ wih,
    const float* __restrict__ bih, const float* __restrict__ bhh,
    f16* __restrict__ xp, int t0, int wid, int ntasks, int stride, int lane) {
  const int q = lane >> 4, l16 = lane & 15;
  const int ct = wid & 7;

  f16x8 BW[4][4];
  float bias[4];
#pragma unroll
  for (int G = 0; G < 4; ++G) {
    int n = G * 128 + ct * 16 + l16;
    bias[G] = (bih[n] + bhh[n]) * SCG[G];
#pragma unroll
    for (int kc = 0; kc < 4; ++kc) {
      const float4* p = (const float4*)(wih + (size_t)n * 128 + kc * 32 + q * 8);
      BW[G][kc] = pack8s(p[0], p[1], SCG[G]);
    }
  }
  for (int task = wid; task < ntasks; task += stride) {
    int g2 = task >> 3;
    int tl = g2 >> 2, btg = g2 & 3;
#pragma unroll
    for (int p = 0; p < 8; ++p) {
      int bt = btg * 8 + p;
      const f16* A = e + ((size_t)(t0 + tl) * 512 + bt * 16 + l16) * 128 + q * 8;
      f16x8 af[4];
#pragma unroll
      for (int kc = 0; kc < 4; ++kc) af[kc] = *(const f16x8*)(A + kc * 32);
      f32x4 acc[4];
#pragma unroll
      for (int G = 0; G < 4; ++G)
        acc[G] = (f32x4){bias[G], bias[G], bias[G], bias[G]};
#pragma unroll
      for (int kc = 0; kc < 4; ++kc)
#pragma unroll
        for (int G = 0; G < 4; ++G)
          acc[G] = MFMA16(af[kc], BW[G][kc], acc[G]);
      f16x8 oA, oB;
#pragma unroll
      for (int r = 0; r < 4; ++r) {
        oA[r]     = (f16)acc[0][r];
        oA[4 + r] = (f16)acc[1][r];
        oB[r]     = (f16)acc[2][r];
        oB[4 + r] = (f16)acc[3][r];
      }
      f16* dst = xp + (size_t)tl * 262144 + bt * 8192 + ct * 1024 + lane * 16;
      *(f16x8*)dst = oA;
      *(f16x8*)(dst + 8) = oB;
    }
  }
}

__global__ __launch_bounds__(256, 2) void k_xp(
    const f16* __restrict__ e, const float* __restrict__ wih,
    const float* __restrict__ bih, const float* __restrict__ bhh,
    f16* __restrict__ xp, int t0) {
  const int nt = gridDim.x * 4;  // one task per wave
  xp_waves(e, wih, bih, bhh, xp, t0,
           blockIdx.x * 4 + (threadIdx.x >> 6), nt, nt, threadIdx.x & 63);
}

// ---------------------------------------------------------------------------
// rec_body: LSTM recurrence (h @ Whh^T + precomputed scaled xp chunk).
// 64 blocks x 8 batch rows, 512 thr. Wave w owns hidden cols w*16..+15 for
// all 4 gates; MFMA A rows 8-15 dead (duplicated, harmless). The 2 valid
// acc elems/lane are spread to all 64 lanes via v_permlane32_swap_b32
// (VALU pipe -- NOT ds_bpermute; keeps the LDS pipe free: A-reads + h-writes
// only). Lane (q,l16) handles rows row0(q)={0,4,2,6}[q]+j, col w*16+l16.
// hs stored DIRECTLY from registers (no LDS round-trip), issued before the
// barrier; barrier drains only lgkmcnt so stores/prefetch stay in flight.
// ---------------------------------------------------------------------------
static __device__ __forceinline__ void rec_body(
    const f16* __restrict__ xp, const float* __restrict__ whh,
    float* __restrict__ hws, float* __restrict__ cws,
    f16* __restrict__ hs, int layer, int t0, int CH, int bt) {
  const int tid = threadIdx.x;
  const int w = tid >> 6, lane = tid & 63, q = lane >> 4, l16 = lane & 15;
  const int row0 = (q & 1) * 4 + (q >> 1) * 2;  // {0,4,2,6}[q]
  __shared__ __align__(16) f16 hlds[2][8][136];  // double-buffered h (8 rows)

  f16x8 BH[4][4];  // Whh B-fragments, pre-scaled per gate
#pragma unroll
  for (int G = 0; G < 4; ++G) {
    int n = G * 128 + w * 16 + l16;
#pragma unroll
    for (int kc = 0; kc < 4; ++kc) {
      const float4* ph = (const float4*)(whh + (size_t)n * 128 + kc * 32 + q * 8);
      BH[G][kc] = pack8s(ph[0], ph[1], SCG[G]);
    }
  }

  float cst0, cst1;
  if (layer == 0 && t0 == 0) {
    cst0 = 0.f; cst1 = 0.f;
    for (int idx = tid; idx < 8 * 136; idx += 512)
      (&hlds[1][0][0])[idx] = (f16)0.f;
  } else {
    const float* cp = cws + ((size_t)(bt * 8 + w) * 64 + lane) * 2;
    cst0 = cp[0]; cst1 = cp[1];
    const float* hp = hws + ((size_t)(bt * 8 + w) * 64 + lane) * 2;
    hlds[1][row0 + 0][w * 16 + l16] = (f16)hp[0];
    hlds[1][row0 + 1][w * 16 + l16] = (f16)hp[1];
  }
  barrier_lds();

  // xp read: block covers old 16-batch group g16=bt>>1, half=bt&1.
  const int qo = (bt & 1) * 2 + (q & 1);
  const f16* xpl = xp + (((size_t)(bt >> 1) * 8 + w) * 64 + qo * 16 + l16) * 16;
  f16x8 xa = *(const f16x8*)(xpl);
  f16x8 xb = *(const f16x8*)(xpl + 8);
  const int t1 = (CH > 1) ? 1 : 0;
  f16x8 n1a = *(const f16x8*)(xpl + (size_t)t1 * 262144);
  f16x8 n1b = *(const f16x8*)(xpl + (size_t)t1 * 262144 + 8);

  float hk0 = 0.f, hk1 = 0.f;
  for (int tl = 0; tl < CH; ++tl) {
    int tn2 = (tl + 2 < CH) ? tl + 2 : CH - 1;
    const f16* xpn = xpl + (size_t)tn2 * 262144;
    f16x8 n2a = *(const f16x8*)(xpn);
    f16x8 n2b = *(const f16x8*)(xpn + 8);

    const int rb = (tl + 1) & 1;
    f16x8 ah[4];
#pragma unroll
    for (int kc = 0; kc < 4; ++kc)
      ah[kc] = *(const f16x8*)&hlds[rb][l16 & 7][kc * 32 + q * 8];

    f32x4 acc[4];
#pragma unroll
    for (int r = 0; r < 4; ++r) {
      acc[0][r] = (float)xa[r];
      acc[1][r] = (float)xa[4 + r];
      acc[2][r] = (float)xb[r];
      acc[3][r] = (float)xb[4 + r];
    }
#pragma unroll
    for (int kc = 0; kc < 4; ++kc)
#pragma unroll
      for (int G = 0; G < 4; ++G)
        acc[G] = MFMA16(ah[kc], BH[G][kc], acc[G]);

    // redistribute via VALU permlane: lane ends with rows row0, row0+1
    float e0[4], e1[4];
#pragma unroll
    for (int G = 0; G < 4; ++G) {
      e0[G] = permswap_lo(acc[G][0], acc[G][2]);
      e1[G] = permswap_lo(acc[G][1], acc[G][3]);
    }

    const int wb = tl & 1;
    f16 h16_0, h16_1;
#pragma unroll
    for (int j = 0; j < 2; ++j) {
      float gi = j ? e1[0] : e0[0];
      float gf = j ? e1[1] : e0[1];
      float gg = j ? e1[2] : e0[2];
      float go = j ? e1[3] : e0[3];
      float cprev = j ? cst1 : cst0;
      // [0]=i', [1]=f', [2]=g'(x2 scale), [3]=o'  (log2 units)
      float ui = __builtin_amdgcn_exp2f(-gi);
      float uf = __builtin_amdgcn_exp2f(-gf);
      float ug = __builtin_amdgcn_exp2f(-fmaxf(gg, -88.f));
      float uo = __builtin_amdgcn_exp2f(-go);
      float sf = __builtin_amdgcn_rcpf(1.0f + uf);
      float p1 = (1.0f - ug) * __builtin_amdgcn_rcpf((1.0f + ui) * (1.0f + ug));
      float cc = sf * cprev + p1;                // new cell state
      if (j) cst1 = cc; else cst0 = cc;
      float ccl = fminf(fmaxf(cc, -30.f), 30.f) * (-2.0f * L2E);
      float ucc = __builtin_amdgcn_exp2f(ccl);
      float hv = (1.0f - ucc) * __builtin_amdgcn_rcpf((1.0f + uo) * (1.0f + ucc));
      if (j) { hk1 = hv; h16_1 = (f16)hv; } else { hk0 = hv; h16_0 = (f16)hv; }
      hlds[wb][row0 + j][w * 16 + l16] = j ? h16_1 : h16_0;
    }
    // hs store straight from registers (no LDS read), before the barrier;
    // vmcnt is never drained in-loop so these overlap the next step.
    if (layer != 0) {
      f16* hp0 = hs + ((size_t)(bt * 8 + row0) * 200 + (t0 + tl)) * 128 + w * 16 + l16;
      hp0[0] = h16_0;
      hp0[25600] = h16_1;  // +1 row = +200*128
    }
    barrier_lds();
    xa = n1a; xb = n1b; n1a = n2a; n1b = n2b;
  }

  float* hp = hws + ((size_t)(bt * 8 + w) * 64 + lane) * 2;
  hp[0] = hk0; hp[1] = hk1;
  float* cp = cws + ((size_t)(bt * 8 + w) * 64 + lane) * 2;
  cp[0] = cst0; cp[1] = cst1;
}

__global__ __launch_bounds__(512, 2) void k_rec(
    const f16* __restrict__ xp, const float* __restrict__ whh,
    float* __restrict__ hws, float* __restrict__ cws,
    f16* __restrict__ hs, int layer, int t0, int CH) {
  rec_body(xp, whh, hws, cws, hs, layer, t0, CH, blockIdx.x);
}

// Merged, grid = 256 (1 block/CU): blocks 0..63 = recurrence chunk
// (layer, t0_r, CH=100, xp_r); blocks 64..255 = persistent x-projection
// (3200 tasks over 1536 waves) into DISJOINT xp_w (A/B ping-pong).
__global__ __launch_bounds__(512, 2) void k_recxp(
    const f16* __restrict__ xp_r, const float* __restrict__ whh,
    float* __restrict__ hws, float* __restrict__ cws,
    f16* __restrict__ hs, int layer, int t0_r,
    const f16* __restrict__ e, const float* __restrict__ wih_n,
    const float* __restrict__ bih_n, const float* __restrict__ bhh_n,
    f16* __restrict__ xp_w, int t0_x) {
  if (blockIdx.x < 64) {
    rec_body(xp_r, whh, hws, cws, hs, layer, t0_r, 100, blockIdx.x);
  } else {
    // 3200 wave-tasks (100 steps), 1536 waves, stride 1536 (mult of 8)
    xp_waves(e, wih_n, bih_n, bhh_n, xp_w, t0_x,
             (blockIdx.x - 64) * 8 + (threadIdx.x >> 6), 3200, 1536,
             threadIdx.x & 63);
  }
}

// ---------------------------------------------------------------------------
// k_head: per-batch fused fc1 -> leaky -> fc2 -> exp -> Sinkhorn -> psi.
// grid=512, block=512 (8 waves), dynamic LDS = 81600 B (2 WG/CU, 16 waves/CU).
// ---------------------------------------------------------------------------
__global__ __launch_bounds__(512, 4) void k_head(
    const f16* __restrict__ hs, const float* __restrict__ wfc1,
    const float* __restrict__ bfc1, const float* __restrict__ wfc2,
    const float* __restrict__ bfc2, float* __restrict__ psi) {
  extern __shared__ char smem[];
  f16* E = (f16*)smem;                      // [200][200]
  f16* o1 = (f16*)(smem + 27200);           // [200][136]
  float* uu = (float*)(smem + 80000);
  float* vv = (float*)(smem + 80800);
  const int b = blockIdx.x, tid = threadIdx.x;
  const int w = tid >> 6, lane = tid & 63, q = lane >> 4, l16 = lane & 15;
  const f16* A = hs + (size_t)b * 200 * 128;

  // fc1 weights: wave w -> cols w*16..+15
  f16x8 BF1[4];
  float bias1;
  {
    int n = w * 16 + l16;
    bias1 = bfc1[n];
#pragma unroll
    for (int kc = 0; kc < 4; ++kc) {
      const float4* p = (const float4*)(wfc1 + (size_t)n * 128 + kc * 32 + q * 8);
      BF1[kc] = pack8(p[0], p[1]);
    }
  }
  // fc2 weights: wave w -> ct = w, w+8
  f16x8 BF2[2][4];
  float bias2[2] = {0.f, 0.f};
#pragma unroll
  for (int ci = 0; ci < 2; ++ci) {
    int ct = w + ci * 8;
    if (ct < 13) {
      int n = ct * 16 + l16; if (n > 199) n = 199;
      bias2[ci] = bfc2[n];
#pragma unroll
      for (int kc = 0; kc < 4; ++kc) {
        const float4* p = (const float4*)(wfc2 + (size_t)n * 128 + kc * 32 + q * 8);
        BF2[ci][kc] = pack8(p[0], p[1]);
      }
    }
  }

  // fc1 -> leaky -> o1
  for (int rt = 0; rt < 13; ++rt) {
    int m = rt * 16 + l16; if (m > 199) m = 199;
    f16x8 af[4];
#pragma unroll
    for (int kc = 0; kc < 4; ++kc)
      af[kc] = *(const f16x8*)(A + (size_t)m * 128 + kc * 32 + q * 8);
    f32x4 acc = (f32x4){bias1, bias1, bias1, bias1};
#pragma unroll
    for (int kc = 0; kc < 4; ++kc) acc = MFMA16(af[kc], BF1[kc], acc);
    int col = w * 16 + l16;
#pragma unroll
    for (int r = 0; r < 4; ++r) {
      int row = rt * 16 + q * 4 + r;
      float vvv = acc[r]; vvv = vvv >= 0.f ? vvv : LEAK * vvv;
      if (row < 200) o1[row * 136 + col] = (f16)vvv;
    }
  }
  __syncthreads();

  // fc2 -> exp -> E
  for (int rt = 0; rt < 13; ++rt) {
    int m = rt * 16 + l16; if (m > 199) m = 199;
    f16x8 af[4];
#pragma unroll
    for (int kc = 0; kc < 4; ++kc)
      af[kc] = *(const f16x8*)&o1[m * 136 + kc * 32 + q * 8];
    __syncthreads();
#pragma unroll
    for (int ci = 0; ci < 2; ++ci) {
      int ct = w + ci * 8;
      if (ct < 13) {
        f32x4 acc = (f32x4){bias2[ci], bias2[ci], bias2[ci], bias2[ci]};
#pragma unroll
        for (int kc = 0; kc < 4; ++kc) acc = MFMA16(af[kc], BF2[ci][kc], acc);
        int col = ct * 16 + l16;
#pragma unroll
        for (int r = 0; r < 4; ++r) {
          int row = rt * 16 + q * 4 + r;
          if (row < 200 && col < 200) E[row * 200 + col] = (f16)__expf(acc[r]);
        }
      }
    }
  }
  __syncthreads();
  if (tid < 200) vv[tid] = 1.0f;
  __syncthreads();

  for (int it = 0; it < 5; ++it) {
    // row phase: r = tid>>1 (0..199), h = tid&1 sums 100 elements
    if (tid < 400) {
      int r = tid >> 1, h = tid & 1;
      const f16* Er = E + r * 200 + h * 100;
      const float* vp = vv + h * 100;
      float s0 = 0.f, s1 = 0.f;
      for (int j = 0; j < 100; j += 4) {
        f16x4 e4 = *(const f16x4*)(Er + j);
        float4 v4 = *(const float4*)(vp + j);
        s0 += (float)e4[0] * v4.x + (float)e4[1] * v4.y;
        s1 += (float)e4[2] * v4.z + (float)e4[3] * v4.w;
      }
      float s = s0 + s1;
      s += __shfl_xor(s, 1);
      if (h == 0) uu[r] = __builtin_amdgcn_rcpf(s);
    }
    __syncthreads();
    // col phase: c4 = tid>>3 (0..49) owns cols c4*4..+3; g = tid&7 owns rows g*25..+24
    if (tid < 400) {
      int c4 = tid >> 3, g = tid & 7;
      const f16* Ec = E + (size_t)(g * 25) * 200 + c4 * 4;
      float a0 = 0.f, a1 = 0.f, a2 = 0.f, a3 = 0.f;
      for (int i = 0; i < 25; ++i) {
        f16x4 e4 = *(const f16x4*)(Ec + i * 200);
        float ui = uu[g * 25 + i];
        a0 += (float)e4[0] * ui;
        a1 += (float)e4[1] * ui;
        a2 += (float)e4[2] * ui;
        a3 += (float)e4[3] * ui;
      }
#pragma unroll
      for (int mk = 1; mk <= 4; mk <<= 1) {
        a0 += __shfl_xor(a0, mk);
        a1 += __shfl_xor(a1, mk);
        a2 += __shfl_xor(a2, mk);
        a3 += __shfl_xor(a3, mk);
      }
      if (g == 0) {
        float4 o;
        o.x = __builtin_amdgcn_rcpf(a0);
        o.y = __builtin_amdgcn_rcpf(a1);
        o.z = __builtin_amdgcn_rcpf(a2);
        o.w = __builtin_amdgcn_rcpf(a3);
        *(float4*)(vv + c4 * 4) = o;
      }
    }
    __syncthreads();
  }

  float* P = psi + (size_t)b * 40000;
  for (int idx4 = tid; idx4 < 10000; idx4 += 512) {
    unsigned i = ((unsigned)idx4 * 5243u) >> 18;
    unsigned jq = (unsigned)idx4 - i * 50u;
    f16x4 e4 = *(const f16x4*)(E + i * 200 + jq * 4);
    float4 v4 = *(const float4*)(vv + jq * 4);
    float ui = uu[i];
    float4 o;
    o.x = ui * (float)e4[0] * v4.x;
    o.y = ui * (float)e4[1] * v4.y;
    o.z = ui * (float)e4[2] * v4.z;
    o.w = ui * (float)e4[3] * v4.w;
    *(float4*)(P + i * 200 + jq * 4) = o;
  }
}

// ---------------------------------------------------------------------------
extern "C" void kernel_launch(void* const* d_in, const int* in_sizes, int n_in,
                              void* d_out, int out_size, void* d_ws, size_t ws_size,
                              hipStream_t stream) {
  const float* x    = (const float*)d_in[0];
  const float* wemb = (const float*)d_in[1];
  const float* bemb = (const float*)d_in[2];
  const float* wih  = (const float*)d_in[3];
  const float* whh  = (const float*)d_in[4];
  const float* bih  = (const float*)d_in[5];
  const float* bhh  = (const float*)d_in[6];
  const float* wfc1 = (const float*)d_in[7];
  const float* bfc1 = (const float*)d_in[8];
  const float* wfc2 = (const float*)d_in[9];
  const float* bfc2 = (const float*)d_in[10];
  float* psi = (float*)d_out;

  char* ws = (char*)d_ws;
  f16*   e   = (f16*)(ws);                  // [200][512][128] f16 = 26,214,400 B
  float* hws = (float*)(ws + 26214400);     // 64x8x64x2 f32       =    262,144 B
  float* cws = (float*)(ws + 26476544);     //                     =    262,144 B
  f16*   hs  = (f16*)(ws + 26738688);       // [512][200][128] f16 = 26,214,400 B
  f16*   xpA = (f16*)(ws + 52953088);       // 100 steps x 512 x 512 f16 = 52,428,800 B
  f16*   xpB = (f16*)(ws + 105381888);      // 100 steps             = 52,428,800 B
  // pipelined total: 157,810,688 B

  const size_t fixed = 52953088;
  const bool pipelined = (ws_size >= 157810688ull);

  (void)hipFuncSetAttribute((const void*)k_head,
                            hipFuncAttributeMaxDynamicSharedMemorySize, 81600);

  k_emb<<<200, 256, 0, stream>>>(x, wemb, bemb, e);

  const float* wih1 = wih + 65536;  const float* whh1 = whh + 65536;
  const float* bih1 = bih + 512;    const float* bhh1 = bhh + 512;

  if (pipelined) {
    // A/B ping-pong, 100-step chunks; rec reads one buffer while the other
    // is being filled for the next chunk (disjoint within every launch).
    k_xp<<<800, 256, 0, stream>>>(e, wih, bih, bhh, xpA, 0);
    k_recxp<<<256, 512, 0, stream>>>(xpA, whh, hws, cws, hs, 0, 0,
                                     e, wih, bih, bhh, xpB, 100);
    k_recxp<<<256, 512, 0, stream>>>(xpB, whh, hws, cws, hs, 0, 100,
                                     e, wih1, bih1, bhh1, xpA, 0);
    k_recxp<<<256, 512, 0, stream>>>(xpA, whh1, hws, cws, hs, 1, 0,
                                     e, wih1, bih1, bhh1, xpB, 100);
    k_rec<<<64, 512, 0, stream>>>(xpB, whh1, hws, cws, hs, 1, 100, 100);
  } else {
    const int cands[] = {100, 50, 40, 25, 20, 10, 8, 5, 4, 2, 1};
    int CH = 1;
    for (int ci = 0; ci < 11; ++ci) {
      if (fixed + (size_t)cands[ci] * 524288 <= ws_size) { CH = cands[ci]; break; }
    }
    for (int l = 0; l < 2; ++l) {
      const float* wih_l = wih + (size_t)l * 65536;
      const float* whh_l = whh + (size_t)l * 65536;
      const float* bih_l = bih + (size_t)l * 512;
      const float* bhh_l = bhh + (size_t)l * 512;
      for (int t0 = 0; t0 < 200; t0 += CH) {
        k_xp<<<CH * 8, 256, 0, stream>>>(e, wih_l, bih_l, bhh_l, xpA, t0);
        k_rec<<<64, 512, 0, stream>>>(xpA, whh_l, hws, cws, hs, l, t0, CH);
      }
    }
  }
  k_head<<<512, 512, 81600, stream>>>(hs, wfc1, bfc1, wfc2, bfc2, psi);
}